// Round 1
// baseline (67.676 us; speedup 1.0000x reference)
//
#include <hip/hip_runtime.h>

// HardNegativeContrastiveLoss, B=8192, D=128, T=0.1, margin=0.5.
//
// Key analytic fact: the reference masks only (i,B+i)/(B+i,i) in neg_sim —
// NOT the diagonal. After normalization the diagonal entry is exactly 1
// (the largest possible cosine sim), so hardest_neg[row] is always the
// diagonal self-similarity / T. The 16384^2 matmul is unnecessary:
//   loss = mean_i over 2B rows of relu(self_sim/T + margin - pos_sim)
// where self_sim = ||z_norm||^2 (== 1 up to fp rounding) and
// pos_sim = dot(z1,z2)/(||z1||*||z2||). Three dot products per row.

constexpr int   kB       = 8192;
constexpr int   kD       = 128;
constexpr float kInvT    = 10.0f;    // 1 / 0.1
constexpr float kMargin  = 0.5f;

__global__ __launch_bounds__(256) void hncl_kernel(const float* __restrict__ z1,
                                                   const float* __restrict__ z2,
                                                   float* __restrict__ out) {
    const int lane         = threadIdx.x & 63;
    const int wave_in_blk  = threadIdx.x >> 6;
    const int waves_per_bk = blockDim.x >> 6;
    const int gwave        = blockIdx.x * waves_per_bk + wave_in_blk;
    const int n_waves      = gridDim.x * waves_per_bk;

    float local = 0.0f;

    // one wave handles one row: 64 lanes x float2 = 128 floats, fully coalesced
    for (int row = gwave; row < kB; row += n_waves) {
        const float2* r1 = reinterpret_cast<const float2*>(z1 + (size_t)row * kD);
        const float2* r2 = reinterpret_cast<const float2*>(z2 + (size_t)row * kD);
        const float2 a = r1[lane];
        const float2 b = r2[lane];

        float d11 = a.x * a.x + a.y * a.y;   // ||z1||^2 partial
        float d22 = b.x * b.x + b.y * b.y;   // ||z2||^2 partial
        float d12 = a.x * b.x + a.y * b.y;   // dot(z1,z2) partial

        // butterfly reduction across the 64-lane wave
        #pragma unroll
        for (int off = 32; off > 0; off >>= 1) {
            d11 += __shfl_down(d11, off, 64);
            d22 += __shfl_down(d22, off, 64);
            d12 += __shfl_down(d12, off, 64);
        }

        if (lane == 0) {
            const float n1 = fmaxf(sqrtf(d11), 1e-12f);
            const float n2 = fmaxf(sqrtf(d22), 1e-12f);
            const float pos = d12 / (n1 * n2);
            const float s1  = d11 / (n1 * n1);   // self-sim of normalized z1 (== 1)
            const float s2  = d22 / (n2 * n2);   // self-sim of normalized z2 (== 1)
            // rows i and B+i of the reference's 2B-row loss
            local += fmaxf(s1 * kInvT + kMargin - pos, 0.0f)
                   + fmaxf(s2 * kInvT + kMargin - pos, 0.0f);
        }
    }

    __shared__ float wsum[4];
    if (lane == 0) wsum[wave_in_blk] = local;
    __syncthreads();
    if (threadIdx.x == 0) {
        float s = 0.0f;
        for (int w = 0; w < waves_per_bk; ++w) s += wsum[w];
        atomicAdd(out, s * (1.0f / (2.0f * (float)kB)));
    }
}

extern "C" void kernel_launch(void* const* d_in, const int* in_sizes, int n_in,
                              void* d_out, int out_size, void* d_ws, size_t ws_size,
                              hipStream_t stream) {
    const float* z1 = reinterpret_cast<const float*>(d_in[0]);
    const float* z2 = reinterpret_cast<const float*>(d_in[1]);
    float* out = reinterpret_cast<float*>(d_out);

    // d_out is poisoned (0xAA) before every timed launch — zero it first.
    // hipMemsetAsync is stream-ordered and graph-capture safe.
    hipMemsetAsync(out, 0, sizeof(float), stream);

    // 512 blocks x 4 waves = 2048 waves -> 4 rows/wave. Memory-bound (8.4 MB).
    hncl_kernel<<<512, 256, 0, stream>>>(z1, z2, out);
}

// Round 2
// 63.339 us; speedup vs baseline: 1.0685x; 1.0685x over previous
//
#include <hip/hip_runtime.h>

// HardNegativeContrastiveLoss, B=8192, D=128, T=0.1, margin=0.5.
//
// Analytic collapse: the reference masks only the (i,B+i)/(B+i,i) pairs in
// neg_sim — NOT the diagonal. After row-normalization the diagonal entry is
// exactly ||z_norm||^2 == 1, the maximum possible cosine similarity, so
// hardest_neg[row] is always the diagonal self-sim / T. The 16384^2 matmul
// collapses to three per-row dot products:
//   loss = mean over 2B rows of relu(self_sim/T + margin - pos_sim)
// with pos_sim = dot(z1,z2)/(||z1||*||z2||), self_sim = d_ii / ||z_i||^2.
//
// Structure: k1 (512 blocks) -> one plain-store partial per block into d_ws
// (overwrites 0xAA poison, no init needed); k2 (1 block) sums the 512
// partials and plain-stores the scaled loss to d_out (no memset, no atomics).
// Rationale: round-1 showed ~27us of unexplained time; 512 same-address
// device-scope atomicAdds serialize at the coherence point — eliminated here.

constexpr int   kB      = 8192;
constexpr int   kD      = 128;
constexpr float kInvT   = 10.0f;     // 1 / 0.1
constexpr float kMargin = 0.5f;
constexpr int   kBlocks = 512;       // k1 grid; d_ws holds kBlocks floats

__global__ __launch_bounds__(256) void hncl_partial(const float* __restrict__ z1,
                                                    const float* __restrict__ z2,
                                                    float* __restrict__ ws) {
    const int lane         = threadIdx.x & 63;
    const int wave_in_blk  = threadIdx.x >> 6;
    const int waves_per_bk = blockDim.x >> 6;   // 4
    const int gwave        = blockIdx.x * waves_per_bk + wave_in_blk;
    const int n_waves      = gridDim.x * waves_per_bk;

    float local = 0.0f;

    // one wave per row: 64 lanes x float2 = 128 floats, fully coalesced
    for (int row = gwave; row < kB; row += n_waves) {
        const float2* r1 = reinterpret_cast<const float2*>(z1 + (size_t)row * kD);
        const float2* r2 = reinterpret_cast<const float2*>(z2 + (size_t)row * kD);
        const float2 a = r1[lane];
        const float2 b = r2[lane];

        float d11 = a.x * a.x + a.y * a.y;   // ||z1||^2 partial
        float d22 = b.x * b.x + b.y * b.y;   // ||z2||^2 partial
        float d12 = a.x * b.x + a.y * b.y;   // dot(z1,z2) partial

        #pragma unroll
        for (int off = 32; off > 0; off >>= 1) {
            d11 += __shfl_down(d11, off, 64);
            d22 += __shfl_down(d22, off, 64);
            d12 += __shfl_down(d12, off, 64);
        }

        if (lane == 0) {
            const float n1 = fmaxf(sqrtf(d11), 1e-12f);
            const float n2 = fmaxf(sqrtf(d22), 1e-12f);
            const float pos = d12 / (n1 * n2);
            const float s1  = d11 / (n1 * n1);   // == 1 up to rounding
            const float s2  = d22 / (n2 * n2);
            local += fmaxf(s1 * kInvT + kMargin - pos, 0.0f)
                   + fmaxf(s2 * kInvT + kMargin - pos, 0.0f);
        }
    }

    __shared__ float wsum[4];
    if (lane == 0) wsum[wave_in_blk] = local;
    __syncthreads();
    if (threadIdx.x == 0) {
        float s = 0.0f;
        for (int w = 0; w < waves_per_bk; ++w) s += wsum[w];
        ws[blockIdx.x] = s;   // plain store — overwrites poison, no atomics
    }
}

__global__ __launch_bounds__(512) void hncl_final(const float* __restrict__ ws,
                                                  float* __restrict__ out) {
    const int lane = threadIdx.x & 63;
    const int wave = threadIdx.x >> 6;           // 8 waves

    float v = ws[threadIdx.x];                   // 512 partials, 1 per thread
    #pragma unroll
    for (int off = 32; off > 0; off >>= 1) v += __shfl_down(v, off, 64);

    __shared__ float wsum[8];
    if (lane == 0) wsum[wave] = v;
    __syncthreads();
    if (threadIdx.x == 0) {
        float s = 0.0f;
        #pragma unroll
        for (int w = 0; w < 8; ++w) s += wsum[w];
        out[0] = s * (1.0f / (2.0f * (float)kB));  // plain store, no memset
    }
}

extern "C" void kernel_launch(void* const* d_in, const int* in_sizes, int n_in,
                              void* d_out, int out_size, void* d_ws, size_t ws_size,
                              hipStream_t stream) {
    const float* z1 = reinterpret_cast<const float*>(d_in[0]);
    const float* z2 = reinterpret_cast<const float*>(d_in[1]);
    float* ws  = reinterpret_cast<float*>(d_ws);
    float* out = reinterpret_cast<float*>(d_out);

    hncl_partial<<<kBlocks, 256, 0, stream>>>(z1, z2, ws);
    hncl_final<<<1, 512, 0, stream>>>(ws, out);
}

// Round 3
// 60.616 us; speedup vs baseline: 1.1165x; 1.0449x over previous
//
#include <hip/hip_runtime.h>

// HardNegativeContrastiveLoss, B=8192, D=128, T=0.1, margin=0.5.
//
// Analytic collapse: the reference masks only the (i,B+i)/(B+i,i) pairs in
// neg_sim — NOT the diagonal. After row-normalization the diagonal entry is
// ||z_norm||^2 == 1, the maximum possible cosine similarity, so
// hardest_neg[row] is always the diagonal self-sim / T. The 16384^2 matmul
// collapses to three per-row dot products:
//   loss = mean over 2B rows of relu(self_sim/T + margin - pos_sim)
//
// R2 profile: dur_us is dominated by the harness's 256 MB d_ws re-poison
// (41 us fillBuffer) + input restores; controllable share is ~13 us.
// This round: float4 loads (16 B/lane), 2 rows/wave via 32-lane halves,
// unrolled so both iterations' loads issue before any reduction.

constexpr int   kB      = 8192;
constexpr int   kD      = 128;
constexpr float kInvT   = 10.0f;     // 1 / 0.1
constexpr float kMargin = 0.5f;
constexpr int   kBlocks = 512;       // k1 grid; d_ws holds kBlocks floats

__global__ __launch_bounds__(256) void hncl_partial(const float* __restrict__ z1,
                                                    const float* __restrict__ z2,
                                                    float* __restrict__ ws) {
    const int lane        = threadIdx.x & 63;
    const int sub         = lane & 31;    // lane within 32-lane half
    const int half        = lane >> 5;    // which row of the wave's pair
    const int wave_in_blk = threadIdx.x >> 6;               // 0..3
    const int gwave       = blockIdx.x * 4 + wave_in_blk;   // 0..2047

    float local = 0.0f;

    // Each wave covers 2 rows/iter (32 lanes x float4 = 128 floats = 1 row).
    // Adjacent rows are contiguous, so the full wave reads 1 KB contiguous.
    #pragma unroll
    for (int iter = 0; iter < 2; ++iter) {
        const int row = gwave * 2 + half + iter * (kB / 2);
        const float4 a = reinterpret_cast<const float4*>(z1 + (size_t)row * kD)[sub];
        const float4 b = reinterpret_cast<const float4*>(z2 + (size_t)row * kD)[sub];

        float d11 = a.x * a.x + a.y * a.y + a.z * a.z + a.w * a.w;
        float d22 = b.x * b.x + b.y * b.y + b.z * b.z + b.w * b.w;
        float d12 = a.x * b.x + a.y * b.y + a.z * b.z + a.w * b.w;

        // reduce within the 32-lane half
        #pragma unroll
        for (int off = 16; off > 0; off >>= 1) {
            d11 += __shfl_down(d11, off, 32);
            d22 += __shfl_down(d22, off, 32);
            d12 += __shfl_down(d12, off, 32);
        }

        if (sub == 0) {
            const float n1 = fmaxf(sqrtf(d11), 1e-12f);
            const float n2 = fmaxf(sqrtf(d22), 1e-12f);
            const float pos = d12 / (n1 * n2);
            const float s1  = d11 / (n1 * n1);   // == 1 up to rounding
            const float s2  = d22 / (n2 * n2);
            local += fmaxf(s1 * kInvT + kMargin - pos, 0.0f)
                   + fmaxf(s2 * kInvT + kMargin - pos, 0.0f);
        }
    }

    __shared__ float wsum[8];
    if (sub == 0) wsum[wave_in_blk * 2 + half] = local;
    __syncthreads();
    if (threadIdx.x == 0) {
        float s = 0.0f;
        #pragma unroll
        for (int i = 0; i < 8; ++i) s += wsum[i];
        ws[blockIdx.x] = s;   // plain store — overwrites poison, no atomics
    }
}

__global__ __launch_bounds__(256) void hncl_final(const float* __restrict__ ws,
                                                  float* __restrict__ out) {
    const int lane = threadIdx.x & 63;
    const int wave = threadIdx.x >> 6;           // 4 waves

    const float2 p = reinterpret_cast<const float2*>(ws)[threadIdx.x];
    float v = p.x + p.y;                         // 512 partials, 2 per thread
    #pragma unroll
    for (int off = 32; off > 0; off >>= 1) v += __shfl_down(v, off, 64);

    __shared__ float wsum[4];
    if (lane == 0) wsum[wave] = v;
    __syncthreads();
    if (threadIdx.x == 0) {
        out[0] = (wsum[0] + wsum[1] + wsum[2] + wsum[3]) * (1.0f / (2.0f * (float)kB));
    }
}

extern "C" void kernel_launch(void* const* d_in, const int* in_sizes, int n_in,
                              void* d_out, int out_size, void* d_ws, size_t ws_size,
                              hipStream_t stream) {
    const float* z1 = reinterpret_cast<const float*>(d_in[0]);
    const float* z2 = reinterpret_cast<const float*>(d_in[1]);
    float* ws  = reinterpret_cast<float*>(d_ws);
    float* out = reinterpret_cast<float*>(d_out);

    hncl_partial<<<kBlocks, 256, 0, stream>>>(z1, z2, ws);
    hncl_final<<<1, 256, 0, stream>>>(ws, out);
}